// Round 7
// baseline (839.625 us; speedup 1.0000x reference)
//
#include <hip/hip_runtime.h>

#define B_ 2048
#define T_ 256
#define F_ 128
#define H_ 64

typedef __attribute__((ext_vector_type(8))) short short8;   // 8 bf16
typedef __attribute__((ext_vector_type(4))) float f32x4;

// pack two floats to adjacent bf16 (RNE): low16 = a, high16 = b
__device__ __forceinline__ unsigned int rne2(float fa, float fb) {
    unsigned int ua = __float_as_uint(fa);
    unsigned int ub = __float_as_uint(fb);
    ua = ua + 0x7fffu + ((ua >> 16) & 1u);
    ub = ub + 0x7fffu + ((ub >> 16) & 1u);
    return (ua >> 16) | (ub & 0xffff0000u);
}
__device__ __forceinline__ float sigmoid_f(float v) {
    return __fdividef(1.0f, 1.0f + __expf(-v));
}
__device__ __forceinline__ float tanh_f(float v) {
    return 1.0f - __fdividef(2.0f, 1.0f + __expf(2.0f * v));  // overflow -> +/-1 correct
}

// Wave-per-row GRU, all-lane gate edition, register-resident gx.
// 256 threads = 4 waves; each WAVE owns ONE batch row. Grid 512 blocks.
// __launch_bounds__(256,1): unified reg budget 512/wave -> allocator takes
// ~215 (demand), no forced 128/128 arch/acc split, NO scratch spill
// (R6: WRITE_SIZE 59MB of spill at bounds(256,2)). 512/215 -> still
// 2 waves/SIMD, same occupancy as R6.
//
// Each lane permanently owns hidden dim d = lq*16+c; h[d] in one fp32 reg.
// gx: bursts of 4 steps, A row m carries tau=m&3 (4x replication) -> lane
//   (lq,c)'s GXC[t][i] = gx(step i, tile t, col c) for EVERY lq. The lane's
//   gate needs tiles {lq,4+lq,8+lq} col c -> held locally; a 12-cndmask
//   compile-time select per gate (once per burst) replaces R6's gxl LDS
//   buffer entirely (-15KB LDS, -48 masked stores, -3 LDS reads/step).
// gh: A rows (c&1)+2*db (parity=hi/lo); 12 N-tiles x 2 K-halves = 24 mfma;
//   whf B-frags loop-invariant in 96 VGPRs; lane selects tile g*4+lq.
// Ordering: wave-private ha + per-step compiler fence (R5/R6-verified).
__global__ __launch_bounds__(256, 1) void gru_fused(
    const float* __restrict__ x, const float* __restrict__ w_ih,
    const float* __restrict__ w_hh, const float* __restrict__ b_ih,
    const float* __restrict__ b_hh, const float* __restrict__ fc_w,
    const float* __restrict__ fc_b, float* __restrict__ out)
{
    __shared__ __align__(16) short wihf[12 * 4 * 64 * 8];   // 48 KB w_ih B-frags
    __shared__ __align__(16) short ha[4][4][72];            // h hi/lo x dbuf, pad 72
    __shared__ float bias_l[12][16];

    const int tid = threadIdx.x;
    const int wv  = tid >> 6;          // 0..3 (wave = batch row)
    const int l   = tid & 63;
    const int c   = l & 15;
    const int lq  = l >> 4;            // 0..3
    const int row = blockIdx.x * 4 + wv;
    const int d   = lq * 16 + c;       // this lane's hidden dim

    // ---- stage w_ih B-frags (verified mapping)
    for (int s = tid; s < 12 * 4 * 64; s += 256) {
        const int n = s >> 8, ks = (s >> 6) & 3, L = s & 63;
        const float* wp = w_ih + (n * 16 + (L & 15)) * F_ + ks * 32 + ((L >> 4) * 8);
        const float4 a = *(const float4*)wp;
        const float4 b = *(const float4*)(wp + 4);
        union { short8 v; unsigned int u[4]; } fr;
        fr.u[0] = rne2(a.x, a.y); fr.u[1] = rne2(a.z, a.w);
        fr.u[2] = rne2(b.x, b.y); fr.u[3] = rne2(b.z, b.w);
        *(short8*)&wihf[s * 8] = fr.v;
    }
    // ---- zero h buffers
    for (int i = tid; i < 4 * 4 * 72; i += 256) ((short*)ha)[i] = 0;
    // ---- gx bias table: b_ih (+ b_hh for r,z)
    if (tid < 192) {
        const int t = tid >> 4, cc = tid & 15;
        const int dd = t * 16 + cc;
        bias_l[t][cc] = b_ih[dd] + (t < 8 ? b_hh[dd] : 0.0f);
    }

    const float bnh = b_hh[128 + d];   // n-gate recurrent bias, lane's dim

    // ---- w_hh B-frags -> registers (loop-invariant, verified mapping)
    short8 whf[12][2];
    #pragma unroll
    for (int t = 0; t < 12; ++t) {
        #pragma unroll
        for (int k2 = 0; k2 < 2; ++k2) {
            const float* wp = w_hh + (t * 16 + c) * H_ + k2 * 32 + lq * 8;
            const float4 a = *(const float4*)wp;
            const float4 b = *(const float4*)(wp + 4);
            union { short8 v; unsigned int u[4]; } fr;
            fr.u[0] = rne2(a.x, a.y); fr.u[1] = rne2(a.z, a.w);
            fr.u[2] = rne2(b.x, b.y); fr.u[3] = rne2(b.z, b.w);
            whf[t][k2] = fr.v;
        }
    }

    // A-side x: row m carries tau = m&3 (lanes c, c^4, c^8, c^12 same addr)
    const float* xlane = x + ((size_t)row * T_ + (c & 3)) * F_ + lq * 8;
    short* hap = &ha[wv][0][0];
    const int ha_rd0 = (c & 1) * 72 + lq * 8;   // +144 for dbuf 1, +32 for k2=1

    __syncthreads();   // staging visible (the ONLY barrier)

    // ---- x staging
    float4 Xh[4];
    short8 af[4];
    auto loadx = [&](const float* lp, int ksb) {
        #pragma unroll
        for (int k2 = 0; k2 < 2; ++k2) {
            Xh[2 * k2]     = *(const float4*)(lp + (ksb + k2) * 32);
            Xh[2 * k2 + 1] = *(const float4*)(lp + (ksb + k2) * 32 + 4);
        }
    };
    auto cvt2 = [&](int ksb) {
        #pragma unroll
        for (int k2 = 0; k2 < 2; ++k2) {
            union { short8 v; unsigned int u[4]; } fr;
            fr.u[0] = rne2(Xh[2 * k2].x,     Xh[2 * k2].y);
            fr.u[1] = rne2(Xh[2 * k2].z,     Xh[2 * k2].w);
            fr.u[2] = rne2(Xh[2 * k2 + 1].x, Xh[2 * k2 + 1].y);
            fr.u[3] = rne2(Xh[2 * k2 + 1].z, Xh[2 * k2 + 1].w);
            af[ksb + k2] = fr.v;
        }
    };
    loadx(xlane, 0); cvt2(0); loadx(xlane, 2); cvt2(2);

    const f32x4 zc = {0.f, 0.f, 0.f, 0.f};
    f32x4 GXS[3];   // selected gx for this burst: GXS[g][si], lane's tile g*4+lq

    auto burst = [&]() {   // gx for 4 steps -> select lane's 3 tiles into GXS
        f32x4 GXC[12];
        #pragma unroll
        for (int t = 0; t < 12; ++t) {
            const float bv = bias_l[t][c];
            GXC[t] = (f32x4){bv, bv, bv, bv};
        }
        #pragma unroll
        for (int ks = 0; ks < 4; ++ks) {
            #pragma unroll
            for (int t = 0; t < 12; ++t)
                GXC[t] = __builtin_amdgcn_mfma_f32_16x16x32_bf16(
                    af[ks], *(const short8*)&wihf[(t * 4 + ks) * 512 + l * 8], GXC[t], 0, 0, 0);
        }
        // lane-local select: GXS[g] = GXC[g*4 + lq]  (compile-time indices)
        #pragma unroll
        for (int g = 0; g < 3; ++g) {
            #pragma unroll
            for (int i = 0; i < 4; ++i) {
                const float a01 = (lq & 1) ? GXC[g * 4 + 1][i] : GXC[g * 4 + 0][i];
                const float a23 = (lq & 1) ? GXC[g * 4 + 3][i] : GXC[g * 4 + 2][i];
                GXS[g][i] = (lq & 2) ? a23 : a01;
            }
        }
    };
    burst();

    float hcur = 0.0f;   // lane's h[d], full fp32, never leaves the register

    #pragma unroll 1
    for (int m = 0; m < 64; ++m) {
        #pragma unroll
        for (int si = 0; si < 4; ++si) {
            const int db = si & 1;               // compile-time double-buffer
            // ---- h A-frags: row parity = hi/lo
            const short8 hA0 = *(const short8*)&hap[ha_rd0 + db * 144];
            const short8 hA1 = *(const short8*)&hap[ha_rd0 + db * 144 + 32];
            // ---- gx scalars for this step (register-resident)
            const float gxr = GXS[0][si];
            const float gxz = GXS[1][si];
            const float gxn = GXS[2][si];
            // ---- gh: 24 MFMA in 3 gate chunks; lane selects tile g*4+lq
            float gh[3];
            #pragma unroll
            for (int g = 0; g < 3; ++g) {
                f32x4 Acc[4];
                #pragma unroll
                for (int t4 = 0; t4 < 4; ++t4)
                    Acc[t4] = __builtin_amdgcn_mfma_f32_16x16x32_bf16(
                        hA0, whf[g * 4 + t4][0], zc, 0, 0, 0);
                #pragma unroll
                for (int t4 = 0; t4 < 4; ++t4)
                    Acc[t4] = __builtin_amdgcn_mfma_f32_16x16x32_bf16(
                        hA1, whf[g * 4 + t4][1], Acc[t4], 0, 0, 0);
                const float s0 = Acc[0][0] + Acc[0][1];   // hi-row + lo-row
                const float s1 = Acc[1][0] + Acc[1][1];
                const float s2 = Acc[2][0] + Acc[2][1];
                const float s3 = Acc[3][0] + Acc[3][1];
                const float a01 = (lq & 1) ? s1 : s0;
                const float a23 = (lq & 1) ? s3 : s2;
                gh[g] = (lq & 2) ? a23 : a01;
            }
            // ---- x prefetch for next macro
            if (si == 1 && m < 63) loadx(xlane + (size_t)(4 * (m + 1)) * F_, 0);
            if (si == 2 && m < 63) { cvt2(0); loadx(xlane + (size_t)(4 * (m + 1)) * F_, 2); }
            if (si == 3 && m < 63) cvt2(2);
            // ---- gate (ALL 64 lanes, one dim each)
            const float r = sigmoid_f(gxr + gh[0]);
            const float z = sigmoid_f(gxz + gh[1]);
            const float n = tanh_f(gxn + r * (gh[2] + bnh));
            hcur = n + z * (hcur - n);
            // ---- split hi/lo bf16, write to the other buffer
            const unsigned int uh = __float_as_uint(hcur);
            const unsigned int rr = uh + 0x7fffu + ((uh >> 16) & 1u);
            const float hif = __uint_as_float(rr & 0xffff0000u);
            const float lof = hcur - hif;
            const unsigned int ul = __float_as_uint(lof);
            const unsigned int r2 = ul + 0x7fffu + ((ul >> 16) & 1u);
            const int wb = (db ^ 1) * 144;
            hap[wb + d]      = (short)(rr >> 16);
            hap[wb + 72 + d] = (short)(r2 >> 16);
            asm volatile("" ::: "memory");       // no ds write->read reorder
        }
        if (m < 63) burst();   // gx for next 4 steps
    }

    // ===== epilogue: each lane holds final h[d] in hcur =====
    {
        float partial = hcur * fc_w[d];
        #pragma unroll
        for (int msk = 1; msk <= 32; msk <<= 1) partial += __shfl_xor(partial, msk, 64);
        if (l == 0) out[row] = partial + fc_b[0];
    }
}

extern "C" void kernel_launch(void* const* d_in, const int* in_sizes, int n_in,
                              void* d_out, int out_size, void* d_ws, size_t ws_size,
                              hipStream_t stream)
{
    (void)in_sizes; (void)n_in; (void)out_size; (void)d_ws; (void)ws_size;
    const float* x    = (const float*)d_in[0];
    const float* w_ih = (const float*)d_in[1];
    const float* w_hh = (const float*)d_in[2];
    const float* b_ih = (const float*)d_in[3];
    const float* b_hh = (const float*)d_in[4];
    const float* fc_w = (const float*)d_in[5];
    const float* fc_b = (const float*)d_in[6];
    float* out = (float*)d_out;

    gru_fused<<<dim3(B_ / 4), 256, 0, stream>>>(
        x, w_ih, w_hh, b_ih, b_hh, fc_w, fc_b, out);
}

// Round 8
// 570.485 us; speedup vs baseline: 1.4718x; 1.4718x over previous
//
#include <hip/hip_runtime.h>

#define B_ 2048
#define T_ 256
#define F_ 128
#define H_ 64

typedef __attribute__((ext_vector_type(8))) short short8;   // 8 bf16
typedef __attribute__((ext_vector_type(4))) float f32x4;

// pack two floats to adjacent bf16 (RNE): low16 = a, high16 = b
__device__ __forceinline__ unsigned int rne2(float fa, float fb) {
    unsigned int ua = __float_as_uint(fa);
    unsigned int ub = __float_as_uint(fb);
    ua = ua + 0x7fffu + ((ua >> 16) & 1u);
    ub = ub + 0x7fffu + ((ub >> 16) & 1u);
    return (ua >> 16) | (ub & 0xffff0000u);
}
__device__ __forceinline__ float sigmoid_f(float v) {
    return __fdividef(1.0f, 1.0f + __expf(-v));
}
__device__ __forceinline__ float tanh_f(float v) {
    return 1.0f - __fdividef(2.0f, 1.0f + __expf(2.0f * v));  // overflow -> +/-1 correct
}

// Wave-per-row GRU, all-lane gates, register-resident gx, 2 blocks/CU.
// 256 threads = 4 waves; each WAVE owns ONE batch row. Grid 512 blocks.
//
// R7 lesson: bounds(256,1) -> >256 regs/wave -> 1 block/CU -> the 512-block
// grid runs in TWO sequential rounds (wall 601us = 2 x ~300us/block).
// R8: bounds(256,2) + transient-register trim so ~190-reg peak fits the
// 256 budget with no spill (R6's spill was a ~230-reg peak at this bound):
//   burst computes gx in 3 PER-GATE passes (16 MFMA each, GXC4 = 16 regs
//   transient instead of 48), selecting into GXS[g] (12 regs) after each.
//
// Each lane permanently owns hidden dim d = lq*16+c; h[d] in one fp32 reg.
// gx: bursts of 4 steps, A row m carries tau=m&3 (4x replication) -> lane
//   (lq,c) holds gx(step i, tile t, col c) for every lq; compile-time
//   cndmask select picks tiles {lq,4+lq,8+lq}.
// gh: A rows (c&1)+2*db (parity=hi/lo); 12 N-tiles x 2 K-halves = 24 mfma;
//   whf B-frags loop-invariant in 96 VGPRs; lane selects tile g*4+lq.
// Ordering: wave-private ha + per-step compiler fence (R5/R6/R7-verified).
__global__ __launch_bounds__(256, 2) void gru_fused(
    const float* __restrict__ x, const float* __restrict__ w_ih,
    const float* __restrict__ w_hh, const float* __restrict__ b_ih,
    const float* __restrict__ b_hh, const float* __restrict__ fc_w,
    const float* __restrict__ fc_b, float* __restrict__ out)
{
    __shared__ __align__(16) short wihf[12 * 4 * 64 * 8];   // 48 KB w_ih B-frags
    __shared__ __align__(16) short ha[4][4][72];            // h hi/lo x dbuf, pad 72
    __shared__ float bias_l[12][16];

    const int tid = threadIdx.x;
    const int wv  = tid >> 6;          // 0..3 (wave = batch row)
    const int l   = tid & 63;
    const int c   = l & 15;
    const int lq  = l >> 4;            // 0..3
    const int row = blockIdx.x * 4 + wv;
    const int d   = lq * 16 + c;       // this lane's hidden dim

    // ---- stage w_ih B-frags (verified mapping)
    for (int s = tid; s < 12 * 4 * 64; s += 256) {
        const int n = s >> 8, ks = (s >> 6) & 3, L = s & 63;
        const float* wp = w_ih + (n * 16 + (L & 15)) * F_ + ks * 32 + ((L >> 4) * 8);
        const float4 a = *(const float4*)wp;
        const float4 b = *(const float4*)(wp + 4);
        union { short8 v; unsigned int u[4]; } fr;
        fr.u[0] = rne2(a.x, a.y); fr.u[1] = rne2(a.z, a.w);
        fr.u[2] = rne2(b.x, b.y); fr.u[3] = rne2(b.z, b.w);
        *(short8*)&wihf[s * 8] = fr.v;
    }
    // ---- zero h buffers
    for (int i = tid; i < 4 * 4 * 72; i += 256) ((short*)ha)[i] = 0;
    // ---- gx bias table: b_ih (+ b_hh for r,z)
    if (tid < 192) {
        const int t = tid >> 4, cc = tid & 15;
        const int dd = t * 16 + cc;
        bias_l[t][cc] = b_ih[dd] + (t < 8 ? b_hh[dd] : 0.0f);
    }

    const float bnh = b_hh[128 + d];   // n-gate recurrent bias, lane's dim

    // ---- w_hh B-frags -> registers (loop-invariant, verified mapping)
    short8 whf[12][2];
    #pragma unroll
    for (int t = 0; t < 12; ++t) {
        #pragma unroll
        for (int k2 = 0; k2 < 2; ++k2) {
            const float* wp = w_hh + (t * 16 + c) * H_ + k2 * 32 + lq * 8;
            const float4 a = *(const float4*)wp;
            const float4 b = *(const float4*)(wp + 4);
            union { short8 v; unsigned int u[4]; } fr;
            fr.u[0] = rne2(a.x, a.y); fr.u[1] = rne2(a.z, a.w);
            fr.u[2] = rne2(b.x, b.y); fr.u[3] = rne2(b.z, b.w);
            whf[t][k2] = fr.v;
        }
    }

    // A-side x: row m carries tau = m&3 (lanes c, c^4, c^8, c^12 same addr)
    const float* xlane = x + ((size_t)row * T_ + (c & 3)) * F_ + lq * 8;
    short* hap = &ha[wv][0][0];
    const int ha_rd0 = (c & 1) * 72 + lq * 8;   // +144 for dbuf 1, +32 for k2=1

    __syncthreads();   // staging visible (the ONLY barrier)

    // ---- x staging
    float4 Xh[4];
    short8 af[4];
    auto loadx = [&](const float* lp, int ksb) {
        #pragma unroll
        for (int k2 = 0; k2 < 2; ++k2) {
            Xh[2 * k2]     = *(const float4*)(lp + (ksb + k2) * 32);
            Xh[2 * k2 + 1] = *(const float4*)(lp + (ksb + k2) * 32 + 4);
        }
    };
    auto cvt2 = [&](int ksb) {
        #pragma unroll
        for (int k2 = 0; k2 < 2; ++k2) {
            union { short8 v; unsigned int u[4]; } fr;
            fr.u[0] = rne2(Xh[2 * k2].x,     Xh[2 * k2].y);
            fr.u[1] = rne2(Xh[2 * k2].z,     Xh[2 * k2].w);
            fr.u[2] = rne2(Xh[2 * k2 + 1].x, Xh[2 * k2 + 1].y);
            fr.u[3] = rne2(Xh[2 * k2 + 1].z, Xh[2 * k2 + 1].w);
            af[ksb + k2] = fr.v;
        }
    };
    loadx(xlane, 0); cvt2(0); loadx(xlane, 2); cvt2(2);

    f32x4 GXS[3];   // selected gx for this burst: GXS[g][si], lane's tile g*4+lq

    auto burst = [&]() {   // gx for 4 steps, PER-GATE passes (16-reg transient)
        #pragma unroll
        for (int g = 0; g < 3; ++g) {
            f32x4 GXC[4];
            #pragma unroll
            for (int t4 = 0; t4 < 4; ++t4) {
                const float bv = bias_l[g * 4 + t4][c];
                GXC[t4] = (f32x4){bv, bv, bv, bv};
            }
            #pragma unroll
            for (int ks = 0; ks < 4; ++ks) {
                #pragma unroll
                for (int t4 = 0; t4 < 4; ++t4)
                    GXC[t4] = __builtin_amdgcn_mfma_f32_16x16x32_bf16(
                        af[ks], *(const short8*)&wihf[((g * 4 + t4) * 4 + ks) * 512 + l * 8],
                        GXC[t4], 0, 0, 0);
            }
            // lane-local select: GXS[g] = GXC[lq]  (compile-time indices)
            #pragma unroll
            for (int i = 0; i < 4; ++i) {
                const float a01 = (lq & 1) ? GXC[1][i] : GXC[0][i];
                const float a23 = (lq & 1) ? GXC[3][i] : GXC[2][i];
                GXS[g][i] = (lq & 2) ? a23 : a01;
            }
        }
    };
    burst();

    const f32x4 zc = {0.f, 0.f, 0.f, 0.f};
    float hcur = 0.0f;   // lane's h[d], full fp32, never leaves the register

    #pragma unroll 1
    for (int m = 0; m < 64; ++m) {
        #pragma unroll
        for (int si = 0; si < 4; ++si) {
            const int db = si & 1;               // compile-time double-buffer
            // ---- h A-frags: row parity = hi/lo
            const short8 hA0 = *(const short8*)&hap[ha_rd0 + db * 144];
            const short8 hA1 = *(const short8*)&hap[ha_rd0 + db * 144 + 32];
            // ---- gx scalars for this step (register-resident)
            const float gxr = GXS[0][si];
            const float gxz = GXS[1][si];
            const float gxn = GXS[2][si];
            // ---- gh: 24 MFMA in 3 gate chunks; lane selects tile g*4+lq
            float gh[3];
            #pragma unroll
            for (int g = 0; g < 3; ++g) {
                f32x4 Acc[4];
                #pragma unroll
                for (int t4 = 0; t4 < 4; ++t4)
                    Acc[t4] = __builtin_amdgcn_mfma_f32_16x16x32_bf16(
                        hA0, whf[g * 4 + t4][0], zc, 0, 0, 0);
                #pragma unroll
                for (int t4 = 0; t4 < 4; ++t4)
                    Acc[t4] = __builtin_amdgcn_mfma_f32_16x16x32_bf16(
                        hA1, whf[g * 4 + t4][1], Acc[t4], 0, 0, 0);
                const float s0 = Acc[0][0] + Acc[0][1];   // hi-row + lo-row
                const float s1 = Acc[1][0] + Acc[1][1];
                const float s2 = Acc[2][0] + Acc[2][1];
                const float s3 = Acc[3][0] + Acc[3][1];
                const float a01 = (lq & 1) ? s1 : s0;
                const float a23 = (lq & 1) ? s3 : s2;
                gh[g] = (lq & 2) ? a23 : a01;
            }
            // ---- x prefetch for next macro
            if (si == 1 && m < 63) loadx(xlane + (size_t)(4 * (m + 1)) * F_, 0);
            if (si == 2 && m < 63) { cvt2(0); loadx(xlane + (size_t)(4 * (m + 1)) * F_, 2); }
            if (si == 3 && m < 63) cvt2(2);
            // ---- gate (ALL 64 lanes, one dim each)
            const float r = sigmoid_f(gxr + gh[0]);
            const float z = sigmoid_f(gxz + gh[1]);
            const float n = tanh_f(gxn + r * (gh[2] + bnh));
            hcur = n + z * (hcur - n);
            // ---- split hi/lo bf16, write to the other buffer
            const unsigned int uh = __float_as_uint(hcur);
            const unsigned int rr = uh + 0x7fffu + ((uh >> 16) & 1u);
            const float hif = __uint_as_float(rr & 0xffff0000u);
            const float lof = hcur - hif;
            const unsigned int ul = __float_as_uint(lof);
            const unsigned int r2 = ul + 0x7fffu + ((ul >> 16) & 1u);
            const int wb = (db ^ 1) * 144;
            hap[wb + d]      = (short)(rr >> 16);
            hap[wb + 72 + d] = (short)(r2 >> 16);
            asm volatile("" ::: "memory");       // no ds write->read reorder
        }
        if (m < 63) burst();   // gx for next 4 steps
    }

    // ===== epilogue: each lane holds final h[d] in hcur =====
    {
        float partial = hcur * fc_w[d];
        #pragma unroll
        for (int msk = 1; msk <= 32; msk <<= 1) partial += __shfl_xor(partial, msk, 64);
        if (l == 0) out[row] = partial + fc_b[0];
    }
}

extern "C" void kernel_launch(void* const* d_in, const int* in_sizes, int n_in,
                              void* d_out, int out_size, void* d_ws, size_t ws_size,
                              hipStream_t stream)
{
    (void)in_sizes; (void)n_in; (void)out_size; (void)d_ws; (void)ws_size;
    const float* x    = (const float*)d_in[0];
    const float* w_ih = (const float*)d_in[1];
    const float* w_hh = (const float*)d_in[2];
    const float* b_ih = (const float*)d_in[3];
    const float* b_hh = (const float*)d_in[4];
    const float* fc_w = (const float*)d_in[5];
    const float* fc_b = (const float*)d_in[6];
    float* out = (float*)d_out;

    gru_fused<<<dim3(B_ / 4), 256, 0, stream>>>(
        x, w_ih, w_hh, b_ih, b_hh, fc_w, fc_b, out);
}